// Round 5
// baseline (1544.386 us; speedup 1.0000x reference)
//
#include <hip/hip_runtime.h>
#include <math.h>

static constexpr int NN   = 100000;   // nodes
static constexpr int NE   = 3200000;  // edges (before self loops)
static constexpr int ET   = NE + NN;  // edges incl self loops
static constexpr int DIN  = 128;
static constexpr int H1   = 8;        // heads layer 1
static constexpr int C1   = 32;       // H1*F1
static constexpr int DOUT = 64;
static constexpr int NG   = 64;       // graphs
static constexpr int NB_SCAN = (NN + 255) / 256;   // 391

__device__ __forceinline__ float lrelu(float x){ return x > 0.f ? x : 0.2f*x; }
// fp32 -> bf16 (RNE) stored as ushort
__device__ __forceinline__ unsigned short f2bf(float x){
  unsigned int u = __float_as_uint(x);
  u += 0x7fffu + ((u >> 16) & 1u);
  return (unsigned short)(u >> 16);
}

// ---------- GEMM1 (x@W1) fused with att1 dots; h1 stored bf16 ----------
__global__ __launch_bounds__(256) void k_gemm1(const float* __restrict__ x,
                                               const float* __restrict__ W,
                                               const float* __restrict__ as1,
                                               const float* __restrict__ ad1,
                                               unsigned short* __restrict__ h1b,
                                               float* __restrict__ a_s,
                                               float* __restrict__ a_d){
  __shared__ float w[DIN * C1];
  for (int i = threadIdx.x; i < DIN * C1; i += 256) w[i] = W[i];
  __syncthreads();
  int idx = blockIdx.x * 256 + threadIdx.x;
  int n = idx >> 5, j = idx & 31;           // j = h*4+f
  const float* xr = x + (size_t)n * DIN;
  float acc = 0.f;
  #pragma unroll
  for (int k = 0; k < DIN; ++k) acc += xr[k] * w[k * C1 + j];
  h1b[idx] = f2bf(acc);
  float s = acc * as1[j], d = acc * ad1[j];
  s += __shfl_xor(s, 1, 64); s += __shfl_xor(s, 2, 64);
  d += __shfl_xor(d, 1, 64); d += __shfl_xor(d, 2, 64);
  if ((j & 3) == 0){ a_s[n * H1 + (j >> 2)] = s; a_d[n * H1 + (j >> 2)] = d; }
}

// ---------- counting sort of edges by dst ----------
__global__ __launch_bounds__(256) void k_init_cnt(int* __restrict__ cnt){
  int n = blockIdx.x * 256 + threadIdx.x;
  if (n < NN) cnt[n] = 1;                   // self-loop
}

__global__ __launch_bounds__(256) void k_hist(const int* __restrict__ ei, int* __restrict__ cnt){
  int e = blockIdx.x * 256 + threadIdx.x;   // e < NE exactly (grid divisible)
  atomicAdd(&cnt[ei[NE + e]], 1);
}

__global__ __launch_bounds__(256) void k_scan_blk(const int* __restrict__ cnt,
                                                  int* __restrict__ tmp, int* __restrict__ btot){
  int g = blockIdx.x * 256 + threadIdx.x;
  int v = (g < NN) ? cnt[g] : 0;
  int lane = threadIdx.x & 63, wv = threadIdx.x >> 6;
  int xv = v;
  #pragma unroll
  for (int o = 1; o < 64; o <<= 1){ int y = __shfl_up(xv, o, 64); if (lane >= o) xv += y; }
  __shared__ int ws[4];
  if (lane == 63) ws[wv] = xv;
  __syncthreads();
  int off = 0;
  for (int i = 0; i < wv; ++i) off += ws[i];
  xv += off;
  if (g < NN) tmp[g] = xv;                        // inclusive within block
  if (threadIdx.x == 255) btot[blockIdx.x] = xv;  // block total
}

__global__ __launch_bounds__(512) void k_scan_top(int* __restrict__ btot){
  int t = threadIdx.x;
  int v = (t < NB_SCAN) ? btot[t] : 0;
  int lane = t & 63, wv = t >> 6;
  int xv = v;
  #pragma unroll
  for (int o = 1; o < 64; o <<= 1){ int y = __shfl_up(xv, o, 64); if (lane >= o) xv += y; }
  __shared__ int ws[8];
  if (lane == 63) ws[wv] = xv;
  __syncthreads();
  int off = 0;
  for (int i = 0; i < wv; ++i) off += ws[i];
  xv += off;
  if (t < NB_SCAN) btot[t] = xv - v;              // exclusive block prefix
}

__global__ __launch_bounds__(256) void k_scan_fin(const int* __restrict__ cnt,
                                                  const int* __restrict__ tmp,
                                                  const int* __restrict__ btot,
                                                  int* __restrict__ row, int* __restrict__ cur){
  int g = blockIdx.x * 256 + threadIdx.x;
  if (g < NN){
    int ex = tmp[g] - cnt[g] + btot[g >> 8];
    row[g] = ex; cur[g] = ex;
  } else if (g == NN){
    row[NN] = ET;
  }
}

__global__ __launch_bounds__(256) void k_scatter(const int* __restrict__ ei,
                                                 int* __restrict__ cur, int2* __restrict__ epair){
  int e = blockIdx.x * 256 + threadIdx.x;
  if (e >= ET) return;
  int s, d;
  if (e < NE) { s = ei[e]; d = ei[NE + e]; }
  else        { s = e - NE; d = s; }
  int pos = atomicAdd(&cur[d], 1);
  epair[pos] = make_int2(s, d);
}

// ---------- layer-1 aggregation: wave per node, 4 edges/iter, bf16 gather ----------
__global__ __launch_bounds__(256) void k_agg1(const int* __restrict__ row,
                                              const int2* __restrict__ epair,
                                              const float* __restrict__ a_s,
                                              const float* __restrict__ a_d,
                                              const unsigned short* __restrict__ h1b,
                                              const float* __restrict__ b1,
                                              float* __restrict__ out1){
  int node = (blockIdx.x * 256 + threadIdx.x) >> 6;
  int lane = threadIdx.x & 63;
  int l16 = lane & 15, grp = lane >> 4;
  int h = l16 >> 1;                          // head for feats (2*l16, 2*l16+1)
  float adv = a_d[node * H1 + h];
  int beg = row[node], end = row[node + 1];
  float accx = 0.f, accy = 0.f, den = 0.f;
  for (int base = beg; base < end; base += 64){
    int idx = base + lane;
    int sv = (idx < end) ? epair[idx].x : INT_MIN;
    int cnt64 = end - base; if (cnt64 > 64) cnt64 = 64;
    #pragma unroll 1
    for (int k0 = 0; k0 < cnt64; k0 += 16){
      float hx[4], hy[4], al[4];
      #pragma unroll
      for (int u = 0; u < 4; ++u){
        int kk = k0 + u * 4 + grp;
        int sraw = __shfl(sv, kk, 64);
        bool live = sraw >= 0;
        int s = live ? sraw : node;
        float a = a_s[s * H1 + h];
        unsigned int hb = *(const unsigned int*)(h1b + (size_t)s * C1 + 2 * l16);
        hx[u] = __uint_as_float(hb << 16);
        hy[u] = __uint_as_float(hb & 0xffff0000u);
        al[u] = live ? __expf(lrelu(a + adv)) : 0.f;
      }
      #pragma unroll
      for (int u = 0; u < 4; ++u){ den += al[u]; accx += al[u] * hx[u]; accy += al[u] * hy[u]; }
    }
  }
  // combine the 4 edge-groups (same l16 -> same feats/head)
  den  += __shfl_xor(den, 16, 64);  den  += __shfl_xor(den, 32, 64);
  accx += __shfl_xor(accx, 16, 64); accx += __shfl_xor(accx, 32, 64);
  accy += __shfl_xor(accy, 16, 64); accy += __shfl_xor(accy, 32, 64);
  if (grp == 0){
    float vx = accx / den + b1[2 * l16];
    float vy = accy / den + b1[2 * l16 + 1];
    vx = vx > 0.f ? vx : expm1f(vx);
    vy = vy > 0.f ? vy : expm1f(vy);
    *(float2*)(out1 + (size_t)node * C1 + 2 * l16) = make_float2(vx, vy);
  }
}

// ---------- GEMM2 (out1@W2) fused with att2 dots; h2 stored bf16 ----------
__global__ __launch_bounds__(256) void k_gemm2(const float* __restrict__ hin,
                                               const float* __restrict__ W,
                                               const float* __restrict__ as2,
                                               const float* __restrict__ ad2,
                                               unsigned short* __restrict__ h2b,
                                               float* __restrict__ a_s,
                                               float* __restrict__ a_d){
  __shared__ float w[C1 * DOUT];
  for (int i = threadIdx.x; i < C1 * DOUT; i += 256) w[i] = W[i];
  __syncthreads();
  int idx = blockIdx.x * 256 + threadIdx.x;
  int n = idx >> 6, j = idx & 63;
  const float* hr = hin + (size_t)n * C1;
  float acc = 0.f;
  #pragma unroll
  for (int k = 0; k < C1; ++k) acc += hr[k] * w[k * DOUT + j];
  h2b[idx] = f2bf(acc);
  float s = acc * as2[j], d = acc * ad2[j];
  #pragma unroll
  for (int o = 1; o < 64; o <<= 1){ s += __shfl_xor(s, o, 64); d += __shfl_xor(d, o, 64); }
  if (j == 0){ a_s[n] = s; a_d[n] = d; }
}

// ---------- per-edge alpha for layer 2 (edge-parallel stream) ----------
__global__ __launch_bounds__(256) void k_edata2(const int2* __restrict__ epair,
                                                const float* __restrict__ a_s,
                                                const float* __restrict__ a_d,
                                                int2* __restrict__ edata){
  int i = blockIdx.x * 256 + threadIdx.x;
  if (i >= ET) return;
  int2 sd = epair[i];
  float al = __expf(lrelu(a_s[sd.x] + a_d[sd.y]));
  edata[i] = make_int2(sd.x, __float_as_int(al));
}

// ---------- layer-2 aggregation + pool: wave per node, 2 edges/iter, bf16 ----------
__global__ __launch_bounds__(256) void k_agg2(const int* __restrict__ row,
                                              const int2* __restrict__ edata,
                                              const unsigned short* __restrict__ h2b,
                                              const int* __restrict__ batch,
                                              float* __restrict__ sums,
                                              float* __restrict__ cntg){
  int node = (blockIdx.x * 256 + threadIdx.x) >> 6;
  int lane = threadIdx.x & 63;
  int l32 = lane & 31, half = lane >> 5;
  int beg = row[node], end = row[node + 1];
  float accx = 0.f, accy = 0.f, den = 0.f;
  for (int base = beg; base < end; base += 64){
    int idx = base + lane;
    int2 ed = (idx < end) ? edata[idx] : make_int2(0, 0);   // alpha bits 0 -> 0.0f
    int cnt64 = end - base; if (cnt64 > 64) cnt64 = 64;
    #pragma unroll 1
    for (int k0 = 0; k0 < cnt64; k0 += 16){
      float hx[8], hy[8], al[8];
      #pragma unroll
      for (int u = 0; u < 8; ++u){
        int kk = k0 + u * 2 + half;
        int sraw = __shfl(ed.x, kk, 64);
        al[u] = __int_as_float(__shfl(ed.y, kk, 64));
        unsigned int hb = *(const unsigned int*)(h2b + (size_t)sraw * DOUT + 2 * l32);
        hx[u] = __uint_as_float(hb << 16);
        hy[u] = __uint_as_float(hb & 0xffff0000u);
      }
      #pragma unroll
      for (int u = 0; u < 8; ++u){ den += al[u]; accx += al[u] * hx[u]; accy += al[u] * hy[u]; }
    }
  }
  den  += __shfl_xor(den, 32, 64);
  accx += __shfl_xor(accx, 32, 64);
  accy += __shfl_xor(accy, 32, 64);
  if (half == 0){
    int g = batch[node];
    atomicAdd(&sums[g * DOUT + 2 * l32],     accx / den);
    atomicAdd(&sums[g * DOUT + 2 * l32 + 1], accy / den);
    if (lane == 0) atomicAdd(&cntg[g], 1.f);
  }
}

__global__ __launch_bounds__(256) void k_final(const float* __restrict__ sums,
                                               const float* __restrict__ cntg,
                                               const float* __restrict__ b2,
                                               float* __restrict__ out){
  int idx = blockIdx.x * 256 + threadIdx.x;
  if (idx >= NG * DOUT) return;
  int g = idx >> 6, f = idx & 63;
  out[idx] = sums[idx] / fmaxf(cntg[g], 1.f) + b2[f];
}

extern "C" void kernel_launch(void* const* d_in, const int* in_sizes, int n_in,
                              void* d_out, int out_size, void* d_ws, size_t ws_size,
                              hipStream_t stream) {
  const float* x   = (const float*)d_in[0];
  const int*   ei  = (const int*)  d_in[1];
  const int*   bat = (const int*)  d_in[2];
  const float* W1  = (const float*)d_in[3];
  const float* as1 = (const float*)d_in[4];
  const float* ad1 = (const float*)d_in[5];
  const float* b1  = (const float*)d_in[6];
  const float* W2  = (const float*)d_in[7];
  const float* as2 = (const float*)d_in[8];
  const float* ad2 = (const float*)d_in[9];
  const float* b2  = (const float*)d_in[10];
  float* out = (float*)d_out;

  char* p = (char*)d_ws;
  auto alloc = [&](size_t bytes){ void* r = p; p += (bytes + 255) & ~(size_t)255; return r; };
  unsigned short* h1b  = (unsigned short*)alloc((size_t)NN * C1 * 2);
  float* a_s1  = (float*)alloc((size_t)NN * H1 * 4);
  float* a_d1  = (float*)alloc((size_t)NN * H1 * 4);
  float* out1  = (float*)alloc((size_t)NN * C1 * 4);
  unsigned short* h2b  = (unsigned short*)alloc((size_t)NN * DOUT * 2);
  float* a_s2  = (float*)alloc(NN * 4);
  float* a_d2  = (float*)alloc(NN * 4);
  int*   row   = (int*)alloc((NN + 1) * 4);
  int*   cur   = (int*)alloc(NN * 4);
  int*   tmp   = (int*)alloc(NN * 4);
  int*   btot  = (int*)alloc(512 * 4);
  int*   cnt   = (int*)alloc(NN * 4);
  int2*  epair = (int2*)alloc((size_t)ET * 8);
  int2*  edata = (int2*)alloc((size_t)ET * 8);
  float* sums  = (float*)alloc(NG * DOUT * 4);
  float* cntg  = (float*)alloc(NG * 4);

  hipMemsetAsync(sums, 0, (NG * DOUT + NG) * 4, stream);  // sums + cntg contiguous
  k_init_cnt<<<(NN + 255) / 256, 256, 0, stream>>>(cnt);

  // node transform 1
  k_gemm1<<<(NN * C1) / 256, 256, 0, stream>>>(x, W1, as1, ad1, h1b, a_s1, a_d1);

  // counting sort by dst
  k_hist    <<<NE / 256, 256, 0, stream>>>(ei, cnt);
  k_scan_blk<<<NB_SCAN, 256, 0, stream>>>(cnt, tmp, btot);
  k_scan_top<<<1, 512, 0, stream>>>(btot);
  k_scan_fin<<<(NN + 256) / 256, 256, 0, stream>>>(cnt, tmp, btot, row, cur);
  k_scatter <<<(ET + 255) / 256, 256, 0, stream>>>(ei, cur, epair);

  // layer 1 aggregate (+bias+ELU)
  k_agg1<<<(NN * 64) / 256, 256, 0, stream>>>(row, epair, a_s1, a_d1, h1b, b1, out1);

  // layer 2
  k_gemm2 <<<(NN * DOUT) / 256, 256, 0, stream>>>(out1, W2, as2, ad2, h2b, a_s2, a_d2);
  k_edata2<<<(ET + 255) / 256, 256, 0, stream>>>(epair, a_s2, a_d2, edata);
  k_agg2  <<<(NN * 64) / 256, 256, 0, stream>>>(row, edata, h2b, bat, sums, cntg);

  // finalize pooled means
  k_final<<<(NG * DOUT + 255) / 256, 256, 0, stream>>>(sums, cntg, b2, out);
}